// Round 7
// baseline (423.148 us; speedup 1.0000x reference)
//
#include <hip/hip_runtime.h>
#include <stdint.h>

// ---------------- problem constants ----------------
#define BATCH 16
#define NCLS 80
#define NPOS 21824            // 16384+4096+1024+256+64
#define POOLN 3320            // 1000+1000+1000+256+64
#define MAXDET 100

// superset segment capacities (multiples of 8)
#define CAP0 4096
#define CAP1 2432
#define CAP2 1024
#define CAP34 320
#define SEG1 (CAP0)                    // 4096
#define SEG2 (CAP0 + CAP1)             // 6528
#define SEG3 (CAP0 + CAP1 + CAP2)      // 7552
#define CAPTOT (SEG3 + CAP34)          // 7872

#define DEC_BPI 341                    // 21824/64 anchors-per-block blocks per image
#define RANK_BPI 16                    // 16 x 512 mykeys = 8192 >= CAPTOT
#define GATHER_BPI 16                  // 16 x 1344 = 21504 anchors (levels 0..2)
#define GATHER_CHUNK 1344              // multiple of 64 -> wave-uniform level

__device__ const int d_lvl_off[5] = {0, 16384, 20480, 21504, 21760};
__device__ const int d_lvl_hw[5]  = {16384, 4096, 1024, 256, 64};

struct Ptrs { const float* p[20]; };

__device__ __forceinline__ void map_lvl(int r, int& level, int& hw) {
  if      (r < 16384) { level = 0; hw = r; }
  else if (r < 20480) { level = 1; hw = r - 16384; }
  else if (r < 21504) { level = 2; hw = r - 20480; }
  else if (r < 21760) { level = 3; hw = r - 21504; }
  else                { level = 4; hw = r - 21760; }
}

// key = (~score_bits)<<32 | (level<<20) | hw; ascending == (score desc, level asc, idx asc).
// Unique per image; ~0ULL is a strictly-greater sentinel.
// digit = (~score_bits) >> 19 is a 13-bit key PREFIX -> {digit <= B} is downward-closed.

// ---------------- kernel 1: decode + fused histogram ----------------
// 4 lanes per anchor (proven R6 math, absmax 0.0). part==0 additionally fires a
// global histogram atomic (per img,level 8192 bins; ~2 adds/bin -> no contention,
// no return -> no stall) replacing the 48-block latency-bound histogram pass.
// Levels 3/4 scatter their deterministic gbuf slots here as before.
__global__ __launch_bounds__(256) void decode_kernel(Ptrs args, uint4* __restrict__ dec,
                                                     unsigned long long* __restrict__ gbuf,
                                                     unsigned* __restrict__ hist) {
  int b  = blockIdx.x / DEC_BPI;
  int bb = blockIdx.x - b * DEC_BPI;
  int t = threadIdx.x;

  int flat0 = bb * 64;                      // level boundaries are all multiples of 64
  int level, hw0;
  map_lvl(flat0, level, hw0);
  int HW = d_lvl_hw[level];
  int aoff = t >> 2, part = t & 3;
  int hw = hw0 + aoff;
  long abase = (long)b * HW + hw;

  const float* cls = args.p[level * 4 + 0];
  const float* reg = args.p[level * 4 + 1];
  const float* ctr = args.p[level * 4 + 2];
  const float* pos = args.p[level * 4 + 3];

  const float4* c4 = (const float4*)(cls + abase * NCLS) + part * 5;
  float4 v0 = c4[0], v1 = c4[1], v2 = c4[2], v3 = c4[3], v4 = c4[4];

  float m = -1e30f; int am = 0;
  int cb = part * 20;
#define CHK(val, j) if ((val) > m) { m = (val); am = cb + (j); }
  CHK(v0.x, 0)  CHK(v0.y, 1)  CHK(v0.z, 2)  CHK(v0.w, 3)
  CHK(v1.x, 4)  CHK(v1.y, 5)  CHK(v1.z, 6)  CHK(v1.w, 7)
  CHK(v2.x, 8)  CHK(v2.y, 9)  CHK(v2.z, 10) CHK(v2.w, 11)
  CHK(v3.x, 12) CHK(v3.y, 13) CHK(v3.z, 14) CHK(v3.w, 15)
  CHK(v4.x, 16) CHK(v4.y, 17) CHK(v4.z, 18) CHK(v4.w, 19)
#undef CHK
#pragma unroll
  for (int d = 1; d <= 2; d <<= 1) {
    float om = __shfl_xor(m, d, 64);
    int   oa = __shfl_xor(am, d, 64);
    if (om > m || (om == m && oa < am)) { m = om; am = oa; }
  }

  if (part == 0) {
    float4 rg = *(const float4*)(reg + abase * 4);
    float  ct = ctr[abase];
    float2 ps = ((const float2*)pos)[abase];

    float e0 = expf(rg.x), e1 = expf(rg.y), e2 = expf(rg.z), e3 = expf(rg.w);
    int x1 = (int)(ps.x - e0);   // C truncation == .astype(int32)
    int y1 = (int)(ps.y - e1);
    int x2 = (int)(ps.x + e2);
    int y2 = (int)(ps.y + e3);
    x1 = max(x1, 0); y1 = max(y1, 0);
    x2 = min(x2, 1023); y2 = min(y2, 1023);

    float sigm = 1.0f / (1.0f + expf(-m));
    float sigc = 1.0f / (1.0f + expf(-ct));
    float score = sqrtf(sigm * sigc);

    uint4 e;
    e.x = __float_as_uint(score);
    e.y = (unsigned)am;
    e.z = (unsigned)(x1 & 0xFFFF) | ((unsigned)y1 << 16);
    e.w = (unsigned)(x2 & 0xFFFF) | ((unsigned)y2 << 16);
    dec[b * NPOS + flat0 + aoff] = e;

    unsigned nsb = ~e.x;
    if (level <= 2) {
      atomicAdd(&hist[(unsigned)(b * 3 + level) * 8192u + (nsb >> 19)], 1u);
    } else {           // deterministic slots for complete levels 3/4
      unsigned long long key =
          ((unsigned long long)nsb << 32) | (unsigned)((level << 20) | hw);
      gbuf[(size_t)b * CAPTOT + SEG3 + ((level == 3) ? hw : 256 + hw)] = key;
    }
  }
}

// ---------------- kernel 2: cutoff (parallel scan of global hist) ----------------
// Smallest B with cum >= 1000 (proven R6 scan logic). 48 tiny blocks.
__global__ __launch_bounds__(256) void cutoff_kernel(const unsigned* __restrict__ hist,
                                                     int* __restrict__ bcut) {
  __shared__ unsigned wpart[4];
  __shared__ int shB;
  int img = blockIdx.x / 3, level = blockIdx.x % 3;
  const unsigned* h = hist + (unsigned)(img * 3 + level) * 8192u;
  int tid = threadIdx.x, lane = tid & 63, wv = tid >> 6;

  unsigned hl[32];
  unsigned s = 0;
#pragma unroll
  for (int k = 0; k < 32; ++k) { hl[k] = h[32 * tid + k]; s += hl[k]; }
  unsigned incl = s;
  for (int d = 1; d < 64; d <<= 1) {
    unsigned v = __shfl_up(incl, d, 64);
    if (lane >= d) incl += v;
  }
  if (lane == 63) wpart[wv] = incl;
  __syncthreads();
  unsigned woff = 0;
  for (int w = 0; w < wv; ++w) woff += wpart[w];
  unsigned excl = woff + incl - s;
  if (excl < 1000u && excl + s >= 1000u) {       // unique crossing thread (N >= 1000)
    unsigned cum = excl; int B = 8191;
#pragma unroll
    for (int k = 0; k < 32; ++k) {
      cum += hl[k];
      if (cum >= 1000u) { B = 32 * tid + k; break; }
    }
    shB = B;
  }
  __syncthreads();
  if (tid == 0) bcut[img * 3 + level] = shB;
}

// ---------------- kernel 3: wide gather of supersets -> single gbuf layout ------
// 16 blocks/image over levels 0..2 (chunks 64-aligned -> wave-uniform level), one
// global atomic counter per (img,level) -> exactly one consistent layout (the R4 fix).
__global__ __launch_bounds__(256) void gather_kernel(const uint4* __restrict__ dec,
                                                     const int* __restrict__ bcut,
                                                     unsigned long long* __restrict__ gbuf,
                                                     int* __restrict__ gcnt) {
  int img = blockIdx.x / GATHER_BPI, bb = blockIdx.x % GATHER_BPI;
  int tid = threadIdx.x, lane = tid & 63;
  int start = bb * GATHER_CHUNK;
  int b0 = bcut[img * 3 + 0], b1 = bcut[img * 3 + 1], b2 = bcut[img * 3 + 2];
  unsigned long long* gb = gbuf + (size_t)img * CAPTOT;

  for (int j = start + tid; j < start + GATHER_CHUNK; j += 256) {
    int level, hw;
    map_lvl(j, level, hw);                       // level wave-uniform (64-aligned groups)
    unsigned nsb = ~dec[img * NPOS + j].x;
    bool sel = (int)(nsb >> 19) <= ((level == 0) ? b0 : (level == 1) ? b1 : b2);
    unsigned long long msk = __ballot(sel);
    if (msk) {
      int nsel = __popcll(msk);
      int bas = 0;
      if (lane == 0) bas = atomicAdd(&gcnt[img * 3 + level], nsel);
      bas = __shfl(bas, 0, 64);
      if (sel) {
        int p = bas + __popcll(msk & ((1ULL << lane) - 1ULL));
        int cap   = (level == 0) ? CAP0 : (level == 1) ? CAP1 : CAP2;
        int sbase = (level == 0) ? 0    : (level == 1) ? SEG1 : SEG2;
        unsigned long long key =
            ((unsigned long long)nsb << 32) | (unsigned)((level << 20) | hw);
        if (p < cap) gb[sbase + p] = key;
      }
    }
  }
}

// ---------------- kernel 4: exact rank -> sorted pool (bit-identical to R6, proven) ----
// pos(x) = sum_l min(n_l,1000) + n_34; level<=2 selected iff own-level n < 1000.
__global__ __launch_bounds__(256) void rank_kernel(const unsigned long long* __restrict__ gbuf,
                                                   const int* __restrict__ gcnt,
                                                   unsigned long long* __restrict__ pool) {
  __shared__ __align__(16) unsigned long long lk[CAPTOT];
  int img = blockIdx.x >> 4, bl = blockIdx.x & 15;
  int tid = threadIdx.x;
  const unsigned long long* gb = gbuf + (size_t)img * CAPTOT;

  int c0 = min(gcnt[img * 3 + 0], CAP0);
  int c1 = min(gcnt[img * 3 + 1], CAP1);
  int c2 = min(gcnt[img * 3 + 2], CAP2);
  int c0p = (c0 + 7) & ~7, c1p = (c1 + 7) & ~7, c2p = (c2 + 7) & ~7;

  for (int i = tid; i < c0p / 2; i += 256)
    ((ulonglong2*)lk)[i] = ((const ulonglong2*)gb)[i];
  for (int i = tid; i < c1p / 2; i += 256)
    ((ulonglong2*)(lk + SEG1))[i] = ((const ulonglong2*)(gb + SEG1))[i];
  for (int i = tid; i < c2p / 2; i += 256)
    ((ulonglong2*)(lk + SEG2))[i] = ((const ulonglong2*)(gb + SEG2))[i];
  for (int i = tid; i < CAP34 / 2; i += 256)
    ((ulonglong2*)(lk + SEG3))[i] = ((const ulonglong2*)(gb + SEG3))[i];
  __syncthreads();
  // overwrite the rounded-up tail (loaded garbage) with strictly-greater sentinels
  if (tid < 8)       { int j = c0 + tid;        if (j < c0p) lk[j] = ~0ULL; }
  else if (tid < 16) { int j = c1 + (tid - 8);  if (j < c1p) lk[SEG1 + j] = ~0ULL; }
  else if (tid < 24) { int j = c2 + (tid - 16); if (j < c2p) lk[SEG2 + j] = ~0ULL; }
  __syncthreads();

  int e0 = bl * 512 + tid, e1 = e0 + 256;
  int seg[2], pos[2] = {0, 0};
  bool val[2], sel[2] = {false, false};
  unsigned long long mk[2];
  int ee[2] = {e0, e1};
#pragma unroll
  for (int r = 0; r < 2; ++r) {
    int e = ee[r];
    int sg, slot;
    if      (e < SEG1)   { sg = 0; slot = e; }
    else if (e < SEG2)   { sg = 1; slot = e - SEG1; }
    else if (e < SEG3)   { sg = 2; slot = e - SEG2; }
    else if (e < CAPTOT) { sg = 3; slot = e - SEG3; }
    else                 { sg = -1; slot = 0; }
    bool v = (sg == 0) ? (slot < c0) : (sg == 1) ? (slot < c1)
           : (sg == 2) ? (slot < c2) : (sg == 3);
    seg[r] = sg; val[r] = v;
    mk[r] = v ? lk[e] : ~0ULL;
  }

#define SEGLOOP(base_, lim_, sidx)                                               \
  { int n0 = 0, n1 = 0;                                                          \
    for (int j = 0; j < (lim_); j += 4) {                                        \
      unsigned long long a0 = lk[(base_) + j + 0], a1 = lk[(base_) + j + 1];     \
      unsigned long long a2 = lk[(base_) + j + 2], a3 = lk[(base_) + j + 3];     \
      n0 += (int)(a0 < mk[0]) + (int)(a1 < mk[0]) +                              \
            (int)(a2 < mk[0]) + (int)(a3 < mk[0]);                               \
      n1 += (int)(a0 < mk[1]) + (int)(a1 < mk[1]) +                              \
            (int)(a2 < mk[1]) + (int)(a3 < mk[1]);                               \
    }                                                                            \
    pos[0] += min(n0, 1000); pos[1] += min(n1, 1000);                            \
    if (seg[0] == (sidx)) sel[0] = n0 < 1000;                                    \
    if (seg[1] == (sidx)) sel[1] = n1 < 1000;                                    \
  }
  SEGLOOP(0,    c0p,   0)
  SEGLOOP(SEG1, c1p,   1)
  SEGLOOP(SEG2, c2p,   2)
  SEGLOOP(SEG3, CAP34, 3)
#undef SEGLOOP

#pragma unroll
  for (int r = 0; r < 2; ++r)
    if (val[r] && sel[r]) pool[img * POOLN + pos[r]] = mk[r];
}

// ---------------- kernel 5: per-image greedy NMS + output (bit-identical, proven) --
__global__ __launch_bounds__(64) void nms_kernel(const uint4* __restrict__ dec,
                                                 const unsigned long long* __restrict__ pool,
                                                 float* __restrict__ out) {
  __shared__ float          s_score[POOLN];
  __shared__ unsigned short s_cls[POOLN];
  __shared__ uint2          s_box[POOLN];
  int img = blockIdx.x;
  int lane = threadIdx.x;

  for (int r = lane; r < POOLN; r += 64) {
    unsigned long long key = pool[img * POOLN + r];
    unsigned low = (unsigned)key;
    int level = (low >> 20) & 7;
    int idx = low & 0xFFFFF;
    uint4 e = dec[img * NPOS + d_lvl_off[level] + idx];
    s_score[r] = __uint_as_float(e.x);
    s_cls[r]   = (unsigned short)e.y;
    s_box[r]   = make_uint2(e.z, e.w);
  }
  __syncthreads();

  float* out_s = out + img * MAXDET;
  float* out_c = out + BATCH * MAXDET + img * MAXDET;
  float* out_b = out + 2 * BATCH * MAXDET + img * MAXDET * 4;

  int kx1[2], ky1[2], kx2[2], ky2[2], kar[2];
  int k = 0;

  for (int i = 0; i < POOLN; ++i) {
    float sc = s_score[i];
    if (!(sc > 0.01f)) break;   // sorted desc: all remaining invalid too
    uint2 bx = s_box[i];
    int x1 = bx.x & 0xFFFF, y1 = bx.x >> 16;
    int x2 = bx.y & 0xFFFF, y2 = bx.y >> 16;
    int area = (x2 - x1) * (y2 - y1);

    bool sup = false;
#pragma unroll
    for (int sidx = 0; sidx < 2; ++sidx) {
      int slot = (sidx << 6) | lane;
      if (slot < k) {
        int xx1 = max(x1, kx1[sidx]), yy1 = max(y1, ky1[sidx]);
        int xx2 = min(x2, kx2[sidx]), yy2 = min(y2, ky2[sidx]);
        int iw = max(xx2 - xx1, 0), ih = max(yy2 - yy1, 0);
        int inter = iw * ih;
        float iou = (float)inter / (float)(area + kar[sidx] - inter);
        sup = sup || (iou > 0.6f);
      }
    }
    if (!__any(sup)) {
      if ((k & 63) == lane) {
        int hi = k >> 6;
        kx1[hi] = x1; ky1[hi] = y1; kx2[hi] = x2; ky2[hi] = y2; kar[hi] = area;
      }
      if (lane == 0) {
        out_s[k] = sc;
        out_c[k] = (float)(int)s_cls[i];
        out_b[k * 4 + 0] = (float)x1;
        out_b[k * 4 + 1] = (float)y1;
        out_b[k * 4 + 2] = (float)x2;
        out_b[k * 4 + 3] = (float)y2;
      }
      ++k;
      if (k == MAXDET) break;
    }
  }

  for (int s = k + lane; s < MAXDET; s += 64) {
    out_s[s] = -1.0f;
    out_c[s] = -1.0f;
    out_b[s * 4 + 0] = -1.0f;
    out_b[s * 4 + 1] = -1.0f;
    out_b[s * 4 + 2] = -1.0f;
    out_b[s * 4 + 3] = -1.0f;
  }
}

// ---------------- launcher ----------------
extern "C" void kernel_launch(void* const* d_in, const int* in_sizes, int n_in,
                              void* d_out, int out_size, void* d_ws, size_t ws_size,
                              hipStream_t stream) {
  Ptrs args;
  for (int i = 0; i < 20; ++i) args.p[i] = (const float*)d_in[i];

  char* ws = (char*)d_ws;
  uint4* dec = (uint4*)ws;                              // 5,586,944 B
  ws += (size_t)BATCH * NPOS * 16;
  unsigned long long* pool = (unsigned long long*)ws;   // 424,960 B
  ws += (size_t)BATCH * POOLN * 8;
  unsigned long long* gbuf = (unsigned long long*)ws;   // 1,007,616 B (16B-aligned)
  ws += (size_t)BATCH * CAPTOT * 8;
  unsigned* hist = (unsigned*)ws;                       // 16*3*8192*4 = 1,572,864 B
  ws += (size_t)BATCH * 3 * 8192 * 4;
  int* gcnt = (int*)ws;                                 // 192 B  (zeroed with hist)
  ws += 192;
  int* bcut = (int*)ws;                                 // 192 B  (written by cutoff)
  float* out = (float*)d_out;

  // zero hist + gcnt in one async memset (graph-capturable)
  hipMemsetAsync(hist, 0, (size_t)BATCH * 3 * 8192 * 4 + 192, stream);

  decode_kernel<<<BATCH * DEC_BPI, 256, 0, stream>>>(args, dec, gbuf, hist);
  cutoff_kernel<<<BATCH * 3, 256, 0, stream>>>(hist, bcut);
  gather_kernel<<<BATCH * GATHER_BPI, 256, 0, stream>>>(dec, bcut, gbuf, gcnt);
  rank_kernel<<<BATCH * RANK_BPI, 256, 0, stream>>>(gbuf, gcnt, pool);
  nms_kernel<<<BATCH, 64, 0, stream>>>(dec, pool, out);
}

// Round 8
// 373.108 us; speedup vs baseline: 1.1341x; 1.1341x over previous
//
#include <hip/hip_runtime.h>
#include <stdint.h>

// ---------------- problem constants ----------------
#define BATCH 16
#define NCLS 80
#define NPOS 21824            // 16384+4096+1024+256+64
#define POOLN 3320            // 1000+1000+1000+256+64
#define MAXDET 100

// superset segment capacities (multiples of 8)
#define CAP0 4096
#define CAP1 2432
#define CAP2 1024
#define CAP34 320
#define SEG1 (CAP0)                    // 4096
#define SEG2 (CAP0 + CAP1)             // 6528
#define SEG3 (CAP0 + CAP1 + CAP2)      // 7552
#define CAPTOT (SEG3 + CAP34)          // 7872

#define DEC_BPI 341                    // 21824/64 anchors-per-block blocks per image
#define RANK_BPI 16                    // 16 x 512 mykeys = 8192 >= CAPTOT
#define GATHER_BPI 16                  // 16 x 1344 = 21504 anchors (levels 0..2)
#define GATHER_CHUNK 1344              // multiple of 64 -> wave-uniform level

#define NBINS 4096                     // digit = nsb >> 20 (12-bit key prefix)
#define HIST_TPI 11                    // hist tasks per image: 8(l0) + 2(l1) + 1(l2)

__device__ const int d_lvl_off[5] = {0, 16384, 20480, 21504, 21760};
__device__ const int d_lvl_hw[5]  = {16384, 4096, 1024, 256, 64};

struct Ptrs { const float* p[20]; };

__device__ __forceinline__ void map_lvl(int r, int& level, int& hw) {
  if      (r < 16384) { level = 0; hw = r; }
  else if (r < 20480) { level = 1; hw = r - 16384; }
  else if (r < 21504) { level = 2; hw = r - 20480; }
  else if (r < 21760) { level = 3; hw = r - 21504; }
  else                { level = 4; hw = r - 21760; }
}

// key = (nsb)<<32 | (level<<20) | hw with nsb = ~score_bits; ascending ==
// (score desc, level asc, idx asc). Unique per image; ~0ULL is a strictly-greater
// sentinel. digit = nsb >> 20 is a 12-bit key PREFIX -> {digit <= B} downward-closed.

// ---------------- kernel 1: decode (exact R6 structure, proven ~70 us) ----------------
// 4 lanes per anchor; 5 independent float4 loads in flight; shfl_xor argmax combine
// with (greater || (equal && lower idx)) -> exact first-occurrence argmax.
// Adds one cold coalesced store of nsb into dense sbuf for the hist/gather passes.
__global__ __launch_bounds__(256) void decode_kernel(Ptrs args, uint4* __restrict__ dec,
                                                     unsigned long long* __restrict__ gbuf,
                                                     int* __restrict__ gcnt,
                                                     unsigned* __restrict__ sbuf) {
  int b  = blockIdx.x / DEC_BPI;
  int bb = blockIdx.x - b * DEC_BPI;
  int t = threadIdx.x;
  if (bb == 0 && t < 3) gcnt[b * 3 + t] = 0;

  int flat0 = bb * 64;                      // level boundaries are all multiples of 64
  int level, hw0;
  map_lvl(flat0, level, hw0);
  int HW = d_lvl_hw[level];
  int aoff = t >> 2, part = t & 3;
  int hw = hw0 + aoff;
  long abase = (long)b * HW + hw;

  const float* cls = args.p[level * 4 + 0];
  const float* reg = args.p[level * 4 + 1];
  const float* ctr = args.p[level * 4 + 2];
  const float* pos = args.p[level * 4 + 3];

  const float4* c4 = (const float4*)(cls + abase * NCLS) + part * 5;
  float4 v0 = c4[0], v1 = c4[1], v2 = c4[2], v3 = c4[3], v4 = c4[4];

  float m = -1e30f; int am = 0;
  int cb = part * 20;
#define CHK(val, j) if ((val) > m) { m = (val); am = cb + (j); }
  CHK(v0.x, 0)  CHK(v0.y, 1)  CHK(v0.z, 2)  CHK(v0.w, 3)
  CHK(v1.x, 4)  CHK(v1.y, 5)  CHK(v1.z, 6)  CHK(v1.w, 7)
  CHK(v2.x, 8)  CHK(v2.y, 9)  CHK(v2.z, 10) CHK(v2.w, 11)
  CHK(v3.x, 12) CHK(v3.y, 13) CHK(v3.z, 14) CHK(v3.w, 15)
  CHK(v4.x, 16) CHK(v4.y, 17) CHK(v4.z, 18) CHK(v4.w, 19)
#undef CHK
#pragma unroll
  for (int d = 1; d <= 2; d <<= 1) {
    float om = __shfl_xor(m, d, 64);
    int   oa = __shfl_xor(am, d, 64);
    if (om > m || (om == m && oa < am)) { m = om; am = oa; }
  }

  if (part == 0) {
    float4 rg = *(const float4*)(reg + abase * 4);
    float  ct = ctr[abase];
    float2 ps = ((const float2*)pos)[abase];

    float e0 = expf(rg.x), e1 = expf(rg.y), e2 = expf(rg.z), e3 = expf(rg.w);
    int x1 = (int)(ps.x - e0);   // C truncation == .astype(int32)
    int y1 = (int)(ps.y - e1);
    int x2 = (int)(ps.x + e2);
    int y2 = (int)(ps.y + e3);
    x1 = max(x1, 0); y1 = max(y1, 0);
    x2 = min(x2, 1023); y2 = min(y2, 1023);

    float sigm = 1.0f / (1.0f + expf(-m));
    float sigc = 1.0f / (1.0f + expf(-ct));
    float score = sqrtf(sigm * sigc);

    uint4 e;
    e.x = __float_as_uint(score);
    e.y = (unsigned)am;
    e.z = (unsigned)(x1 & 0xFFFF) | ((unsigned)y1 << 16);
    e.w = (unsigned)(x2 & 0xFFFF) | ((unsigned)y2 << 16);
    dec[b * NPOS + flat0 + aoff] = e;

    unsigned nsb = ~e.x;
    sbuf[b * NPOS + flat0 + aoff] = nsb;
    if (level >= 3) {    // deterministic slots for complete levels 3/4
      unsigned long long key =
          ((unsigned long long)nsb << 32) | (unsigned)((level << 20) | hw);
      gbuf[(size_t)b * CAPTOT + SEG3 + ((level == 3) ? hw : 256 + hw)] = key;
    }
  }
}

// ---------------- kernel 2: wide histogram (LDS-local, merge nonzero bins) ------
// 11 blocks/image: 8 chunks of level 0, 2 of level 1, 1 of level 2. Dense sbuf reads.
__global__ __launch_bounds__(256) void hist_kernel(const unsigned* __restrict__ sbuf,
                                                   unsigned* __restrict__ ghist) {
  __shared__ unsigned h[NBINS];
  int img = blockIdx.x / HIST_TPI, task = blockIdx.x % HIST_TPI;
  int level, start, n;
  if      (task < 8)  { level = 0; start = task * 2048;       n = 2048; }
  else if (task < 10) { level = 1; start = (task - 8) * 2048; n = 2048; }
  else                { level = 2; start = 0;                 n = 1024; }
  int tid = threadIdx.x;

  for (int i = tid; i < NBINS; i += 256) h[i] = 0;
  __syncthreads();
  const unsigned* base = sbuf + img * NPOS + d_lvl_off[level] + start;
  for (int i = tid; i < n; i += 256)
    atomicAdd(&h[base[i] >> 20], 1u);
  __syncthreads();
  unsigned* gh = ghist + (unsigned)(img * 3 + level) * NBINS;
  for (int i = tid; i < NBINS; i += 256) {
    unsigned v = h[i];
    if (v) atomicAdd(&gh[i], v);
  }
}

// ---------------- kernel 3: cutoff (parallel scan; proven R7 logic, 4096 bins) ----
__global__ __launch_bounds__(256) void cutoff_kernel(const unsigned* __restrict__ ghist,
                                                     int* __restrict__ bcut) {
  __shared__ unsigned wpart[4];
  __shared__ int shB;
  int img = blockIdx.x / 3, level = blockIdx.x % 3;
  const unsigned* h = ghist + (unsigned)(img * 3 + level) * NBINS;
  int tid = threadIdx.x, lane = tid & 63, wv = tid >> 6;

  unsigned hl[16];
  unsigned s = 0;
#pragma unroll
  for (int k = 0; k < 16; ++k) { hl[k] = h[16 * tid + k]; s += hl[k]; }
  unsigned incl = s;
  for (int d = 1; d < 64; d <<= 1) {
    unsigned v = __shfl_up(incl, d, 64);
    if (lane >= d) incl += v;
  }
  if (lane == 63) wpart[wv] = incl;
  __syncthreads();
  unsigned woff = 0;
  for (int w = 0; w < wv; ++w) woff += wpart[w];
  unsigned excl = woff + incl - s;
  if (excl < 1000u && excl + s >= 1000u) {       // unique crossing thread (N >= 1000)
    unsigned cum = excl; int B = NBINS - 1;
#pragma unroll
    for (int k = 0; k < 16; ++k) {
      cum += hl[k];
      if (cum >= 1000u) { B = 16 * tid + k; break; }
    }
    shB = B;
  }
  __syncthreads();
  if (tid == 0) bcut[img * 3 + level] = shB;
}

// ---------------- kernel 4: wide gather -> single gbuf layout (proven R7) ------
// 16 blocks/image over levels 0..2 (chunks 64-aligned -> wave-uniform level), one
// global atomic counter per (img,level) -> exactly one consistent layout.
__global__ __launch_bounds__(256) void gather_kernel(const unsigned* __restrict__ sbuf,
                                                     const int* __restrict__ bcut,
                                                     unsigned long long* __restrict__ gbuf,
                                                     int* __restrict__ gcnt) {
  int img = blockIdx.x / GATHER_BPI, bb = blockIdx.x % GATHER_BPI;
  int tid = threadIdx.x, lane = tid & 63;
  int start = bb * GATHER_CHUNK;
  int b0 = bcut[img * 3 + 0], b1 = bcut[img * 3 + 1], b2 = bcut[img * 3 + 2];
  unsigned long long* gb = gbuf + (size_t)img * CAPTOT;

  for (int j = start + tid; j < start + GATHER_CHUNK; j += 256) {
    int level, hw;
    map_lvl(j, level, hw);                       // level wave-uniform (64-aligned groups)
    unsigned nsb = sbuf[img * NPOS + j];
    bool sel = (int)(nsb >> 20) <= ((level == 0) ? b0 : (level == 1) ? b1 : b2);
    unsigned long long msk = __ballot(sel);
    if (msk) {
      int nsel = __popcll(msk);
      int bas = 0;
      if (lane == 0) bas = atomicAdd(&gcnt[img * 3 + level], nsel);
      bas = __shfl(bas, 0, 64);
      if (sel) {
        int p = bas + __popcll(msk & ((1ULL << lane) - 1ULL));
        int cap   = (level == 0) ? CAP0 : (level == 1) ? CAP1 : CAP2;
        int sbase = (level == 0) ? 0    : (level == 1) ? SEG1 : SEG2;
        unsigned long long key =
            ((unsigned long long)nsb << 32) | (unsigned)((level << 20) | hw);
        if (p < cap) gb[sbase + p] = key;
      }
    }
  }
}

// ---------------- kernel 5: exact rank -> sorted pool (bit-identical, proven) ----
// pos(x) = sum_l min(n_l,1000) + n_34; level<=2 selected iff own-level n < 1000.
__global__ __launch_bounds__(256) void rank_kernel(const unsigned long long* __restrict__ gbuf,
                                                   const int* __restrict__ gcnt,
                                                   unsigned long long* __restrict__ pool) {
  __shared__ __align__(16) unsigned long long lk[CAPTOT];
  int img = blockIdx.x >> 4, bl = blockIdx.x & 15;
  int tid = threadIdx.x;
  const unsigned long long* gb = gbuf + (size_t)img * CAPTOT;

  int c0 = min(gcnt[img * 3 + 0], CAP0);
  int c1 = min(gcnt[img * 3 + 1], CAP1);
  int c2 = min(gcnt[img * 3 + 2], CAP2);
  int c0p = (c0 + 7) & ~7, c1p = (c1 + 7) & ~7, c2p = (c2 + 7) & ~7;

  for (int i = tid; i < c0p / 2; i += 256)
    ((ulonglong2*)lk)[i] = ((const ulonglong2*)gb)[i];
  for (int i = tid; i < c1p / 2; i += 256)
    ((ulonglong2*)(lk + SEG1))[i] = ((const ulonglong2*)(gb + SEG1))[i];
  for (int i = tid; i < c2p / 2; i += 256)
    ((ulonglong2*)(lk + SEG2))[i] = ((const ulonglong2*)(gb + SEG2))[i];
  for (int i = tid; i < CAP34 / 2; i += 256)
    ((ulonglong2*)(lk + SEG3))[i] = ((const ulonglong2*)(gb + SEG3))[i];
  __syncthreads();
  // overwrite the rounded-up tail (loaded garbage) with strictly-greater sentinels
  if (tid < 8)       { int j = c0 + tid;        if (j < c0p) lk[j] = ~0ULL; }
  else if (tid < 16) { int j = c1 + (tid - 8);  if (j < c1p) lk[SEG1 + j] = ~0ULL; }
  else if (tid < 24) { int j = c2 + (tid - 16); if (j < c2p) lk[SEG2 + j] = ~0ULL; }
  __syncthreads();

  int e0 = bl * 512 + tid, e1 = e0 + 256;
  int seg[2], pos[2] = {0, 0};
  bool val[2], sel[2] = {false, false};
  unsigned long long mk[2];
  int ee[2] = {e0, e1};
#pragma unroll
  for (int r = 0; r < 2; ++r) {
    int e = ee[r];
    int sg, slot;
    if      (e < SEG1)   { sg = 0; slot = e; }
    else if (e < SEG2)   { sg = 1; slot = e - SEG1; }
    else if (e < SEG3)   { sg = 2; slot = e - SEG2; }
    else if (e < CAPTOT) { sg = 3; slot = e - SEG3; }
    else                 { sg = -1; slot = 0; }
    bool v = (sg == 0) ? (slot < c0) : (sg == 1) ? (slot < c1)
           : (sg == 2) ? (slot < c2) : (sg == 3);
    seg[r] = sg; val[r] = v;
    mk[r] = v ? lk[e] : ~0ULL;
  }

#define SEGLOOP(base_, lim_, sidx)                                               \
  { int n0 = 0, n1 = 0;                                                          \
    for (int j = 0; j < (lim_); j += 4) {                                        \
      unsigned long long a0 = lk[(base_) + j + 0], a1 = lk[(base_) + j + 1];     \
      unsigned long long a2 = lk[(base_) + j + 2], a3 = lk[(base_) + j + 3];     \
      n0 += (int)(a0 < mk[0]) + (int)(a1 < mk[0]) +                              \
            (int)(a2 < mk[0]) + (int)(a3 < mk[0]);                               \
      n1 += (int)(a0 < mk[1]) + (int)(a1 < mk[1]) +                              \
            (int)(a2 < mk[1]) + (int)(a3 < mk[1]);                               \
    }                                                                            \
    pos[0] += min(n0, 1000); pos[1] += min(n1, 1000);                            \
    if (seg[0] == (sidx)) sel[0] = n0 < 1000;                                    \
    if (seg[1] == (sidx)) sel[1] = n1 < 1000;                                    \
  }
  SEGLOOP(0,    c0p,   0)
  SEGLOOP(SEG1, c1p,   1)
  SEGLOOP(SEG2, c2p,   2)
  SEGLOOP(SEG3, CAP34, 3)
#undef SEGLOOP

#pragma unroll
  for (int r = 0; r < 2; ++r)
    if (val[r] && sel[r]) pool[img * POOLN + pos[r]] = mk[r];
}

// ---------------- kernel 6: per-image greedy NMS + output (bit-identical, proven) --
__global__ __launch_bounds__(64) void nms_kernel(const uint4* __restrict__ dec,
                                                 const unsigned long long* __restrict__ pool,
                                                 float* __restrict__ out) {
  __shared__ float          s_score[POOLN];
  __shared__ unsigned short s_cls[POOLN];
  __shared__ uint2          s_box[POOLN];
  int img = blockIdx.x;
  int lane = threadIdx.x;

  for (int r = lane; r < POOLN; r += 64) {
    unsigned long long key = pool[img * POOLN + r];
    unsigned low = (unsigned)key;
    int level = (low >> 20) & 7;
    int idx = low & 0xFFFFF;
    uint4 e = dec[img * NPOS + d_lvl_off[level] + idx];
    s_score[r] = __uint_as_float(e.x);
    s_cls[r]   = (unsigned short)e.y;
    s_box[r]   = make_uint2(e.z, e.w);
  }
  __syncthreads();

  float* out_s = out + img * MAXDET;
  float* out_c = out + BATCH * MAXDET + img * MAXDET;
  float* out_b = out + 2 * BATCH * MAXDET + img * MAXDET * 4;

  int kx1[2], ky1[2], kx2[2], ky2[2], kar[2];
  int k = 0;

  for (int i = 0; i < POOLN; ++i) {
    float sc = s_score[i];
    if (!(sc > 0.01f)) break;   // sorted desc: all remaining invalid too
    uint2 bx = s_box[i];
    int x1 = bx.x & 0xFFFF, y1 = bx.x >> 16;
    int x2 = bx.y & 0xFFFF, y2 = bx.y >> 16;
    int area = (x2 - x1) * (y2 - y1);

    bool sup = false;
#pragma unroll
    for (int sidx = 0; sidx < 2; ++sidx) {
      int slot = (sidx << 6) | lane;
      if (slot < k) {
        int xx1 = max(x1, kx1[sidx]), yy1 = max(y1, ky1[sidx]);
        int xx2 = min(x2, kx2[sidx]), yy2 = min(y2, ky2[sidx]);
        int iw = max(xx2 - xx1, 0), ih = max(yy2 - yy1, 0);
        int inter = iw * ih;
        float iou = (float)inter / (float)(area + kar[sidx] - inter);
        sup = sup || (iou > 0.6f);
      }
    }
    if (!__any(sup)) {
      if ((k & 63) == lane) {
        int hi = k >> 6;
        kx1[hi] = x1; ky1[hi] = y1; kx2[hi] = x2; ky2[hi] = y2; kar[hi] = area;
      }
      if (lane == 0) {
        out_s[k] = sc;
        out_c[k] = (float)(int)s_cls[i];
        out_b[k * 4 + 0] = (float)x1;
        out_b[k * 4 + 1] = (float)y1;
        out_b[k * 4 + 2] = (float)x2;
        out_b[k * 4 + 3] = (float)y2;
      }
      ++k;
      if (k == MAXDET) break;
    }
  }

  for (int s = k + lane; s < MAXDET; s += 64) {
    out_s[s] = -1.0f;
    out_c[s] = -1.0f;
    out_b[s * 4 + 0] = -1.0f;
    out_b[s * 4 + 1] = -1.0f;
    out_b[s * 4 + 2] = -1.0f;
    out_b[s * 4 + 3] = -1.0f;
  }
}

// ---------------- launcher ----------------
extern "C" void kernel_launch(void* const* d_in, const int* in_sizes, int n_in,
                              void* d_out, int out_size, void* d_ws, size_t ws_size,
                              hipStream_t stream) {
  Ptrs args;
  for (int i = 0; i < 20; ++i) args.p[i] = (const float*)d_in[i];

  char* ws = (char*)d_ws;
  uint4* dec = (uint4*)ws;                              // 5,586,944 B
  ws += (size_t)BATCH * NPOS * 16;
  unsigned long long* pool = (unsigned long long*)ws;   // 424,960 B
  ws += (size_t)BATCH * POOLN * 8;
  unsigned long long* gbuf = (unsigned long long*)ws;   // 1,007,616 B (16B-aligned)
  ws += (size_t)BATCH * CAPTOT * 8;
  unsigned* sbuf = (unsigned*)ws;                       // 16*21824*4 = 1,396,736 B
  ws += (size_t)BATCH * NPOS * 4;
  unsigned* ghist = (unsigned*)ws;                      // 48*4096*4 = 786,432 B
  ws += (size_t)BATCH * 3 * NBINS * 4;
  int* gcnt = (int*)ws;                                 // 192 B  (zeroed by decode)
  ws += 192;
  int* bcut = (int*)ws;                                 // 192 B  (written by cutoff)
  float* out = (float*)d_out;

  hipMemsetAsync(ghist, 0, (size_t)BATCH * 3 * NBINS * 4, stream);

  decode_kernel<<<BATCH * DEC_BPI, 256, 0, stream>>>(args, dec, gbuf, gcnt, sbuf);
  hist_kernel<<<BATCH * HIST_TPI, 256, 0, stream>>>(sbuf, ghist);
  cutoff_kernel<<<BATCH * 3, 256, 0, stream>>>(ghist, bcut);
  gather_kernel<<<BATCH * GATHER_BPI, 256, 0, stream>>>(sbuf, bcut, gbuf, gcnt);
  rank_kernel<<<BATCH * RANK_BPI, 256, 0, stream>>>(gbuf, gcnt, pool);
  nms_kernel<<<BATCH, 64, 0, stream>>>(dec, pool, out);
}